// Round 1
// baseline (456.965 us; speedup 1.0000x reference)
//
#include <hip/hip_runtime.h>
#include <cstdint>
#include <cstddef>

// Problem constants
#define BB 4
#define TT 4096
#define EE 1024
#define HH 16
#define SSLOTS 64
#define DD 64
#define MM (BB*TT)   // 16384

typedef unsigned short u16;
typedef __attribute__((ext_vector_type(8))) short s16x8;     // 8 bf16 (4 VGPRs) MFMA frag
typedef __attribute__((ext_vector_type(4))) float f32x4;     // MFMA acc
typedef __attribute__((ext_vector_type(8))) unsigned short us8v;
typedef __attribute__((ext_vector_type(4))) unsigned short us4v;

#define MFMA16(a, b, c) __builtin_amdgcn_mfma_f32_16x16x32_bf16((a), (b), (c), 0, 0, 0)

__device__ __forceinline__ u16 f2bf(float x) {
  union { float f; uint32_t u; } c; c.f = x;
  uint32_t u = c.u;
  u += 0x7fffu + ((u >> 16) & 1u);   // round-to-nearest-even
  return (u16)(u >> 16);
}

// async global->LDS, 16B per lane. LDS dest must be base + lane*16 (wave-contiguous).
__device__ __forceinline__ void async16(const void* g, void* l) {
  auto lp = reinterpret_cast<__attribute__((address_space(3))) void*>(
      reinterpret_cast<uintptr_t>(l));
  auto gp = reinterpret_cast<const __attribute__((address_space(1))) void*>(
      reinterpret_cast<uintptr_t>(g));
  __builtin_amdgcn_global_load_lds(gp, lp, 16, 0, 0);
}

// ---------------- conversion kernels ----------------
__global__ __launch_bounds__(256) void k_cvt(const float* __restrict__ s,
                                             u16* __restrict__ d, int n) {
  int i = (blockIdx.x * 256 + threadIdx.x) * 4;
  if (i + 3 >= n + 1) { if (i >= n) return; }
  float4 v = *(const float4*)(s + i);
  us4v o = { f2bf(v.x), f2bf(v.y), f2bf(v.z), f2bf(v.w) };
  *(us4v*)(d + i) = o;
}

__global__ __launch_bounds__(256) void k_rope(float* __restrict__ rc, float* __restrict__ rs) {
  int i = blockIdx.x * 256 + threadIdx.x;
  if (i >= TT * 32) return;
  int t = i >> 5, f = i & 31;
  double invf = pow(10000.0, -(double)(2 * f) / 64.0);
  double th = fmod((double)t * invf, 6.28318530717958647692528676655900577);
  rc[i] = (float)cos(th);
  rs[i] = (float)sin(th);
}

// ---------------- shared GEMM mainloop: C(128x128) = A(128xK) * B(128xK)^T ----------------
__device__ __forceinline__ void gemm_tile_128(const u16* __restrict__ Ablk,
                                              const u16* __restrict__ Bblk,
                                              int K, u16* As, u16* Bs,
                                              f32x4 acc[4][4]) {
  const int tid = threadIdx.x;
  const int lane = tid & 63, wave = tid >> 6;
  const int l16 = lane & 15, q8 = (lane >> 4) * 8;
  const int wm = (wave >> 1) * 64, wn = (wave & 1) * 64;
  const int ar = tid >> 2, ac = (tid & 3) * 8;
  const u16* Ag0 = Ablk + (size_t)ar * K + ac;
  const u16* Ag1 = Ablk + (size_t)(ar + 64) * K + ac;
  const u16* Bg0 = Bblk + (size_t)ar * K + ac;
  const u16* Bg1 = Bblk + (size_t)(ar + 64) * K + ac;
  u16* Al0 = As + ar * 32 + ac;
  u16* Al1 = As + (ar + 64) * 32 + ac;
  u16* Bl0 = Bs + ar * 32 + ac;
  u16* Bl1 = Bs + (ar + 64) * 32 + ac;

  for (int k0 = 0; k0 < K; k0 += 32) {
    async16(Ag0 + k0, Al0);
    async16(Ag1 + k0, Al1);
    async16(Bg0 + k0, Bl0);
    async16(Bg1 + k0, Bl1);
    __syncthreads();
    s16x8 af[4], bf[4];
#pragma unroll
    for (int i = 0; i < 4; ++i) {
      af[i] = *(const s16x8*)(As + (wm + i * 16 + l16) * 32 + q8);
      bf[i] = *(const s16x8*)(Bs + (wn + i * 16 + l16) * 32 + q8);
    }
#pragma unroll
    for (int im = 0; im < 4; ++im)
#pragma unroll
      for (int in = 0; in < 4; ++in)
        acc[im][in] = MFMA16(af[im], bf[in], acc[im][in]);
    __syncthreads();
  }
}

// ---------------- fused QKV GEMM + RoPE epilogue ----------------
// A: x bf16 [16384][1024]; Bw: [Wq;Wk;Wv] bf16 [3072][1024]
// outputs q16/k16/v16 bf16 in [b][h][t][d]
__global__ __launch_bounds__(256) void k_gemm_qkv(const u16* __restrict__ A,
                                                  const u16* __restrict__ Bw,
                                                  u16* __restrict__ q16,
                                                  u16* __restrict__ k16,
                                                  u16* __restrict__ v16,
                                                  const float* __restrict__ rc,
                                                  const float* __restrict__ rs) {
  __shared__ u16 As[128 * 32];
  __shared__ u16 Bs[128 * 32];
  f32x4 acc[4][4];
#pragma unroll
  for (int i = 0; i < 4; ++i)
#pragma unroll
    for (int j = 0; j < 4; ++j) acc[i][j] = (f32x4){0.f, 0.f, 0.f, 0.f};

  const int m0 = blockIdx.x * 128;
  const int n0g = blockIdx.y * 128;
  gemm_tile_128(A + (size_t)m0 * 1024, Bw + (size_t)n0g * 1024, 1024, As, Bs, acc);

  const int tid = threadIdx.x, lane = tid & 63, wave = tid >> 6;
  const int l16 = lane & 15, q4 = lane >> 4;
  const int wm = (wave >> 1) * 64, wn = (wave & 1) * 64;
  const int which = n0g >> 10;       // 0=Q,1=K,2=V (uniform per block)
  const int nb = n0g & 1023;
  u16* dst = (which == 0) ? q16 : ((which == 1) ? k16 : v16);

#pragma unroll
  for (int im = 0; im < 4; ++im)
#pragma unroll
    for (int in = 0; in < 4; ++in)
#pragma unroll
      for (int reg = 0; reg < 4; ++reg) {
        float v = acc[im][in][reg];
        int m = m0 + wm + im * 16 + q4 * 4 + reg;
        int nn = nb + wn + in * 16 + l16;
        int b = m >> 12, t = m & 4095;
        int h = nn >> 6, d = nn & 63;
        float p = __shfl_xor(v, 1);   // partner d^1 (same t,h)
        if (which < 2) {
          int fi = t * 32 + (d & 31);
          float r = (d & 1) ? p : -p; // rot[2i]=-x[2i+1], rot[2i+1]=x[2i]
          v = v * rc[fi] + r * rs[fi];
        }
        dst[((size_t)(b * HH + h) * TT + t) * 64 + d] = f2bf(v);
      }
}

// ---------------- plain out GEMM (fp32 epilogue) ----------------
__global__ __launch_bounds__(256) void k_gemm_out(const u16* __restrict__ A,
                                                  const u16* __restrict__ Bw,
                                                  float* __restrict__ C) {
  __shared__ u16 As[128 * 32];
  __shared__ u16 Bs[128 * 32];
  f32x4 acc[4][4];
#pragma unroll
  for (int i = 0; i < 4; ++i)
#pragma unroll
    for (int j = 0; j < 4; ++j) acc[i][j] = (f32x4){0.f, 0.f, 0.f, 0.f};

  const int m0 = blockIdx.x * 128;
  const int n0 = blockIdx.y * 128;
  gemm_tile_128(A + (size_t)m0 * 1024, Bw + (size_t)n0 * 1024, 1024, As, Bs, acc);

  const int tid = threadIdx.x, lane = tid & 63, wave = tid >> 6;
  const int l16 = lane & 15, q4 = lane >> 4;
  const int wm = (wave >> 1) * 64, wn = (wave & 1) * 64;
#pragma unroll
  for (int im = 0; im < 4; ++im)
#pragma unroll
    for (int in = 0; in < 4; ++in)
#pragma unroll
      for (int reg = 0; reg < 4; ++reg) {
        int m = m0 + wm + im * 16 + q4 * 4 + reg;
        int n = n0 + wn + in * 16 + l16;
        C[(size_t)m * 1024 + n] = acc[im][in][reg];
      }
}

// ---------------- stage 2: write logits -> softmax -> slot_state accumulation ----------------
// grid: 1024 blocks = 64 (b*h) x 16 t-blocks; each block loops 2 chunks of 128 t
__global__ __launch_bounds__(256) void k_stage2(const u16* __restrict__ K16g,
                                                const u16* __restrict__ V16g,
                                                const float* __restrict__ SKg,
                                                float* __restrict__ SSb) {
  const int tid = threadIdx.x, lane = tid & 63, wave = tid >> 6;
  const int l16 = lane & 15, q4 = lane >> 4, q8 = q4 * 8;
  const int bh = blockIdx.x >> 4, cb = blockIdx.x & 15;
  const int h = bh & 15;

  __shared__ u16 Ks[128 * 88];    // [t][d] stride 88 (16B-aligned rows, ~2-way banks)
  __shared__ u16 Vs[64 * 136];    // [d][t] stride 136
  __shared__ u16 SKs[64 * 88];    // [s][d]
  u16* ww = Ks;                   // reuse as WW^T [s=64][t=128] stride 136 (fits in Ks)

  const float* skh = SKg + (size_t)h * (SSLOTS * DD);
  for (int i = tid; i < 4096; i += 256)
    SKs[(i >> 6) * 88 + (i & 63)] = f2bf(skh[i]);

  f32x4 a2[4];
#pragma unroll
  for (int in = 0; in < 4; ++in) a2[in] = (f32x4){0.f, 0.f, 0.f, 0.f};

  const int w32 = wave * 32;
  for (int cc = 0; cc < 2; ++cc) {
    const int tg0 = cb * 256 + cc * 128;
    __syncthreads();   // SKs visible (cc=0) / prev-iter LDS reads done (cc=1)

    const u16* ks = K16g + ((size_t)bh * TT + tg0) * 64;
    for (int idx = tid; idx < 1024; idx += 256) {
      int t = idx >> 3, p = idx & 7;
      *(uint4*)&Ks[t * 88 + p * 8] = *(const uint4*)(ks + (size_t)t * 64 + p * 8);
    }
    const u16* vsrc = V16g + ((size_t)bh * TT + tg0) * 64;
    for (int idx = tid; idx < 1024; idx += 256) {
      int t = idx & 127, dg = idx >> 7;
      us8v vv = *(const us8v*)(vsrc + (size_t)t * 64 + dg * 8);
#pragma unroll
      for (int j = 0; j < 8; ++j) Vs[(dg * 8 + j) * 136 + t] = vv[j];
    }
    __syncthreads();

    // MFMA1: WL[t][s] = K . SK^T   (wave owns 32 t-rows)
    f32x4 a1[2][4];
#pragma unroll
    for (int im = 0; im < 2; ++im)
#pragma unroll
      for (int in = 0; in < 4; ++in) a1[im][in] = (f32x4){0.f, 0.f, 0.f, 0.f};
#pragma unroll
    for (int ksx = 0; ksx < 2; ++ksx) {
      s16x8 afr0 = *(const s16x8*)&Ks[(w32 + l16) * 88 + ksx * 32 + q8];
      s16x8 afr1 = *(const s16x8*)&Ks[(w32 + 16 + l16) * 88 + ksx * 32 + q8];
#pragma unroll
      for (int in = 0; in < 4; ++in) {
        s16x8 bfr = *(const s16x8*)&SKs[(in * 16 + l16) * 88 + ksx * 32 + q8];
        a1[0][in] = MFMA16(afr0, bfr, a1[0][in]);
        a1[1][in] = MFMA16(afr1, bfr, a1[1][in]);
      }
    }
    __syncthreads();   // all waves done reading Ks before ww overwrite

    // softmax over s (64) per t-row; write WW^T bf16 into ww[s][t]
#pragma unroll
    for (int im = 0; im < 2; ++im)
#pragma unroll
      for (int reg = 0; reg < 4; ++reg) {
        float v0 = a1[im][0][reg] * 0.125f, v1 = a1[im][1][reg] * 0.125f;
        float v2 = a1[im][2][reg] * 0.125f, v3 = a1[im][3][reg] * 0.125f;
        float mx = fmaxf(fmaxf(v0, v1), fmaxf(v2, v3));
#pragma unroll
        for (int m = 1; m < 16; m <<= 1) mx = fmaxf(mx, __shfl_xor(mx, m));
        float e0 = __expf(v0 - mx), e1 = __expf(v1 - mx);
        float e2 = __expf(v2 - mx), e3 = __expf(v3 - mx);
        float sm = e0 + e1 + e2 + e3;
#pragma unroll
        for (int m = 1; m < 16; m <<= 1) sm += __shfl_xor(sm, m);
        float inv = 1.0f / sm;
        int tl = w32 + im * 16 + q4 * 4 + reg;
        ww[(l16) * 136 + tl]      = f2bf(e0 * inv);
        ww[(16 + l16) * 136 + tl] = f2bf(e1 * inv);
        ww[(32 + l16) * 136 + tl] = f2bf(e2 * inv);
        ww[(48 + l16) * 136 + tl] = f2bf(e3 * inv);
      }
    __syncthreads();

    // MFMA2: SS[s][d] += WW^T . V   (wave owns 16 s-rows, k = 128 t)
#pragma unroll
    for (int ksx = 0; ksx < 4; ++ksx) {
      s16x8 afr = *(const s16x8*)&ww[(wave * 16 + l16) * 136 + ksx * 32 + q8];
#pragma unroll
      for (int in = 0; in < 4; ++in) {
        s16x8 bfr = *(const s16x8*)&Vs[(in * 16 + l16) * 136 + ksx * 32 + q8];
        a2[in] = MFMA16(afr, bfr, a2[in]);
      }
    }
  }

  const float invT = 1.0f / (float)TT;
#pragma unroll
  for (int in = 0; in < 4; ++in)
#pragma unroll
    for (int reg = 0; reg < 4; ++reg) {
      int s = wave * 16 + q4 * 4 + reg;
      int d = in * 16 + l16;
      atomicAdd(&SSb[(size_t)bh * 4096 + s * 64 + d], a2[in][reg] * invT);
    }
}

// ---------------- stage 3: read logits -> softmax -> read_out ----------------
// grid: 1024 blocks = 64 (b*h) x 16 chunks of 256 t
__global__ __launch_bounds__(256) void k_stage3(const u16* __restrict__ Q16g,
                                                const float* __restrict__ SSg,
                                                u16* __restrict__ RO) {
  const int tid = threadIdx.x, lane = tid & 63, wave = tid >> 6;
  const int l16 = lane & 15, q4 = lane >> 4, q8 = q4 * 8;
  const int bh = blockIdx.x >> 4, ck = blockIdx.x & 15;
  const int b = bh >> 4, h = bh & 15;
  const int tg0 = ck * 256;

  __shared__ u16 Qs[256 * 88];      // [t][d]; reused as RW [t][s] (same rows)
  __shared__ u16 ss_sd[64 * 88];    // SS[s][d]
  __shared__ u16 ss_ds[64 * 88];    // SS^T[d][s]
  u16* RWs = Qs;

  const float* ssp = SSg + (size_t)bh * 4096;
  for (int i = tid; i < 4096; i += 256) {
    u16 u = f2bf(ssp[i]);
    int s = i >> 6, d = i & 63;
    ss_sd[s * 88 + d] = u;
    ss_ds[d * 88 + s] = u;
  }
  const u16* qsrc = Q16g + ((size_t)bh * TT + tg0) * 64;
  for (int idx = tid; idx < 2048; idx += 256) {
    int t = idx >> 3, p = idx & 7;
    *(uint4*)&Qs[t * 88 + p * 8] = *(const uint4*)(qsrc + (size_t)t * 64 + p * 8);
  }
  __syncthreads();

  const int w64 = wave * 64;
  // MFMA3: RL[t][s] = Q . SS^T
  f32x4 a3[4][4];
#pragma unroll
  for (int i = 0; i < 4; ++i)
#pragma unroll
    for (int j = 0; j < 4; ++j) a3[i][j] = (f32x4){0.f, 0.f, 0.f, 0.f};
#pragma unroll
  for (int ksx = 0; ksx < 2; ++ksx) {
    s16x8 afr[4];
#pragma unroll
    for (int im = 0; im < 4; ++im)
      afr[im] = *(const s16x8*)&Qs[(w64 + im * 16 + l16) * 88 + ksx * 32 + q8];
#pragma unroll
    for (int in = 0; in < 4; ++in) {
      s16x8 bfr = *(const s16x8*)&ss_sd[(in * 16 + l16) * 88 + ksx * 32 + q8];
#pragma unroll
      for (int im = 0; im < 4; ++im) a3[im][in] = MFMA16(afr[im], bfr, a3[im][in]);
    }
  }
  __syncthreads();

  // softmax over s, write RW[t][s] bf16
#pragma unroll
  for (int im = 0; im < 4; ++im)
#pragma unroll
    for (int reg = 0; reg < 4; ++reg) {
      float v0 = a3[im][0][reg] * 0.125f, v1 = a3[im][1][reg] * 0.125f;
      float v2 = a3[im][2][reg] * 0.125f, v3 = a3[im][3][reg] * 0.125f;
      float mx = fmaxf(fmaxf(v0, v1), fmaxf(v2, v3));
#pragma unroll
      for (int m = 1; m < 16; m <<= 1) mx = fmaxf(mx, __shfl_xor(mx, m));
      float e0 = __expf(v0 - mx), e1 = __expf(v1 - mx);
      float e2 = __expf(v2 - mx), e3 = __expf(v3 - mx);
      float sm = e0 + e1 + e2 + e3;
#pragma unroll
      for (int m = 1; m < 16; m <<= 1) sm += __shfl_xor(sm, m);
      float inv = 1.0f / sm;
      int tl = w64 + im * 16 + q4 * 4 + reg;
      RWs[tl * 88 + l16]      = f2bf(e0 * inv);
      RWs[tl * 88 + 16 + l16] = f2bf(e1 * inv);
      RWs[tl * 88 + 32 + l16] = f2bf(e2 * inv);
      RWs[tl * 88 + 48 + l16] = f2bf(e3 * inv);
    }
  __syncthreads();

  // MFMA4: RO[t][d] = RW . SS
  f32x4 a4[4][4];
#pragma unroll
  for (int i = 0; i < 4; ++i)
#pragma unroll
    for (int j = 0; j < 4; ++j) a4[i][j] = (f32x4){0.f, 0.f, 0.f, 0.f};
#pragma unroll
  for (int ksx = 0; ksx < 2; ++ksx) {
    s16x8 afr[4];
#pragma unroll
    for (int im = 0; im < 4; ++im)
      afr[im] = *(const s16x8*)&RWs[(w64 + im * 16 + l16) * 88 + ksx * 32 + q8];
#pragma unroll
    for (int in = 0; in < 4; ++in) {
      s16x8 bfr = *(const s16x8*)&ss_ds[(in * 16 + l16) * 88 + ksx * 32 + q8];
#pragma unroll
      for (int im = 0; im < 4; ++im) a4[im][in] = MFMA16(afr[im], bfr, a4[im][in]);
    }
  }

  // epilogue: RO bf16 [m][e] with m=b*T+t, e=h*64+d
#pragma unroll
  for (int im = 0; im < 4; ++im)
#pragma unroll
    for (int in = 0; in < 4; ++in)
#pragma unroll
      for (int reg = 0; reg < 4; ++reg) {
        int t = tg0 + w64 + im * 16 + q4 * 4 + reg;
        int d = in * 16 + l16;
        RO[((size_t)b * TT + t) * 1024 + h * 64 + d] = f2bf(a4[im][in][reg]);
      }
}

// ---------------- launch ----------------
extern "C" void kernel_launch(void* const* d_in, const int* in_sizes, int n_in,
                              void* d_out, int out_size, void* d_ws, size_t ws_size,
                              hipStream_t stream) {
  const float* x  = (const float*)d_in[0];
  const float* Wq = (const float*)d_in[1];
  const float* Wk = (const float*)d_in[2];
  const float* Wv = (const float*)d_in[3];
  const float* Wo = (const float*)d_in[4];
  const float* SK = (const float*)d_in[5];
  float* out = (float*)d_out;

  // workspace carve (needs ~145 MB)
  char* w = (char*)d_ws;
  u16* x16 = (u16*)w;   w += (size_t)MM * EE * 2;          // 33.5 MB
  u16* W16 = (u16*)w;   w += (size_t)3 * EE * EE * 2;      // 6.3 MB
  u16* Wo16 = (u16*)w;  w += (size_t)EE * EE * 2;          // 2.1 MB
  u16* Q16 = (u16*)w;   w += (size_t)BB * HH * TT * DD * 2; // 33.5 MB
  u16* K16 = (u16*)w;   w += (size_t)BB * HH * TT * DD * 2;
  u16* V16 = (u16*)w;   w += (size_t)BB * HH * TT * DD * 2;
  float* SSb = (float*)w; w += (size_t)BB * HH * SSLOTS * DD * 4; // 1 MB
  float* rc = (float*)w;  w += (size_t)TT * 32 * 4;
  float* rs = (float*)w;  w += (size_t)TT * 32 * 4;
  u16* RO16 = x16;  // x16 dead after QKV GEMM

  if ((size_t)(w - (char*)d_ws) > ws_size) return;  // ws too small -> loud failure

  k_cvt<<<16384, 256, 0, stream>>>(x, x16, MM * EE);
  k_cvt<<<1024, 256, 0, stream>>>(Wq, W16, EE * EE);
  k_cvt<<<1024, 256, 0, stream>>>(Wk, W16 + EE * EE, EE * EE);
  k_cvt<<<1024, 256, 0, stream>>>(Wv, W16 + 2 * EE * EE, EE * EE);
  k_cvt<<<1024, 256, 0, stream>>>(Wo, Wo16, EE * EE);
  k_rope<<<512, 256, 0, stream>>>(rc, rs);

  k_gemm_qkv<<<dim3(MM / 128, 3 * EE / 128), 256, 0, stream>>>(x16, W16, Q16, K16, V16, rc, rs);

  hipMemsetAsync(SSb, 0, (size_t)BB * HH * SSLOTS * DD * 4, stream);
  k_stage2<<<1024, 256, 0, stream>>>(K16, V16, SK, SSb);
  k_stage3<<<1024, 256, 0, stream>>>(Q16, SSb, RO16);

  k_gemm_out<<<dim3(MM / 128, EE / 128), 256, 0, stream>>>(RO16, Wo16, out);
}

// Round 2
// 381.866 us; speedup vs baseline: 1.1967x; 1.1967x over previous
//
#include <hip/hip_runtime.h>
#include <cstdint>
#include <cstddef>

// Problem constants
#define BB 4
#define TT 4096
#define EE 1024
#define HH 16
#define SSLOTS 64
#define DD 64
#define MM (BB*TT)   // 16384

typedef unsigned short u16;
typedef __attribute__((ext_vector_type(8))) short s16x8;     // 8 bf16 (4 VGPRs) MFMA frag
typedef __attribute__((ext_vector_type(4))) float f32x4;     // MFMA acc
typedef __attribute__((ext_vector_type(8))) unsigned short us8v;
typedef __attribute__((ext_vector_type(4))) unsigned short us4v;

#define MFMA16(a, b, c) __builtin_amdgcn_mfma_f32_16x16x32_bf16((a), (b), (c), 0, 0, 0)

__device__ __forceinline__ u16 f2bf(float x) {
  union { float f; uint32_t u; } c; c.f = x;
  uint32_t u = c.u;
  u += 0x7fffu + ((u >> 16) & 1u);   // round-to-nearest-even
  return (u16)(u >> 16);
}

__device__ __forceinline__ float bf2f(u16 x) {
  union { uint32_t u; float f; } c; c.u = ((uint32_t)x) << 16;
  return c.f;
}

// async global->LDS, 16B per lane. LDS dest must be base + lane*16 (wave-contiguous).
__device__ __forceinline__ void async16(const void* g, void* l) {
  auto lp = reinterpret_cast<__attribute__((address_space(3))) void*>(
      reinterpret_cast<uintptr_t>(l));
  auto gp = reinterpret_cast<const __attribute__((address_space(1))) void*>(
      reinterpret_cast<uintptr_t>(g));
  __builtin_amdgcn_global_load_lds(gp, lp, 16, 0, 0);
}

// Apply RoPE to an 8-wide bf16 chunk at feature offset d0=p*8 of row t.
// cos/sin column for feature d is (d & 31); for a chunk, the 8 columns are
// contiguous starting at (p*8)&31 (never wraps: start<=24).
__device__ __forceinline__ us8v rope8(us8v kv, const float* __restrict__ rcp,
                                      const float* __restrict__ rsp) {
  float e[8];
#pragma unroll
  for (int m = 0; m < 8; ++m) e[m] = bf2f((u16)kv[m]);
  us8v o;
#pragma unroll
  for (int j = 0; j < 4; ++j) {
    float c0 = rcp[2 * j], c1 = rcp[2 * j + 1];
    float s0 = rsp[2 * j], s1 = rsp[2 * j + 1];
    o[2 * j]     = f2bf(e[2 * j] * c0 - e[2 * j + 1] * s0);
    o[2 * j + 1] = f2bf(e[2 * j + 1] * c1 + e[2 * j] * s1);
  }
  return o;
}

// ---------------- conversion kernels ----------------
__global__ __launch_bounds__(256) void k_cvt(const float* __restrict__ s,
                                             u16* __restrict__ d, int n) {
  int i = (blockIdx.x * 256 + threadIdx.x) * 4;
  if (i >= n) return;
  float4 v = *(const float4*)(s + i);
  us4v o = { f2bf(v.x), f2bf(v.y), f2bf(v.z), f2bf(v.w) };
  *(us4v*)(d + i) = o;
}

__global__ __launch_bounds__(256) void k_rope(float* __restrict__ rc, float* __restrict__ rs) {
  int i = blockIdx.x * 256 + threadIdx.x;
  if (i >= TT * 32) return;
  int t = i >> 5, f = i & 31;
  double invf = pow(10000.0, -(double)(2 * f) / 64.0);
  double th = fmod((double)t * invf, 6.28318530717958647692528676655900577);
  rc[i] = (float)cos(th);
  rs[i] = (float)sin(th);
}

// ---------------- shared GEMM mainloop: C(128x128) = A(128xK) * B(128xK)^T ----------------
__device__ __forceinline__ void gemm_tile_128(const u16* __restrict__ Ablk,
                                              const u16* __restrict__ Bblk,
                                              int K, u16* As, u16* Bs,
                                              f32x4 acc[4][4]) {
  const int tid = threadIdx.x;
  const int lane = tid & 63, wave = tid >> 6;
  const int l16 = lane & 15, q8 = (lane >> 4) * 8;
  const int wm = (wave >> 1) * 64, wn = (wave & 1) * 64;
  const int ar = tid >> 2, ac = (tid & 3) * 8;
  const u16* Ag0 = Ablk + (size_t)ar * K + ac;
  const u16* Ag1 = Ablk + (size_t)(ar + 64) * K + ac;
  const u16* Bg0 = Bblk + (size_t)ar * K + ac;
  const u16* Bg1 = Bblk + (size_t)(ar + 64) * K + ac;
  u16* Al0 = As + ar * 32 + ac;
  u16* Al1 = As + (ar + 64) * 32 + ac;
  u16* Bl0 = Bs + ar * 32 + ac;
  u16* Bl1 = Bs + (ar + 64) * 32 + ac;

  for (int k0 = 0; k0 < K; k0 += 32) {
    async16(Ag0 + k0, Al0);
    async16(Ag1 + k0, Al1);
    async16(Bg0 + k0, Bl0);
    async16(Bg1 + k0, Bl1);
    __syncthreads();
    s16x8 af[4], bf[4];
#pragma unroll
    for (int i = 0; i < 4; ++i) {
      af[i] = *(const s16x8*)(As + (wm + i * 16 + l16) * 32 + q8);
      bf[i] = *(const s16x8*)(Bs + (wn + i * 16 + l16) * 32 + q8);
    }
#pragma unroll
    for (int im = 0; im < 4; ++im)
#pragma unroll
      for (int in = 0; in < 4; ++in)
        acc[im][in] = MFMA16(af[im], bf[in], acc[im][in]);
    __syncthreads();
  }
}

// ---------------- fused QKV GEMM (no rope here; rope applied in stage2/3) ----------------
// A: x bf16 [16384][1024]; Bw: [Wq;Wk;Wv] bf16 [3072][1024]
// outputs q16/k16/v16 bf16 in [b][h][t][d] (q,k PRE-rope)
__global__ __launch_bounds__(256) void k_gemm_qkv(const u16* __restrict__ A,
                                                  const u16* __restrict__ Bw,
                                                  u16* __restrict__ q16,
                                                  u16* __restrict__ k16,
                                                  u16* __restrict__ v16) {
  __shared__ u16 As[128 * 32];
  __shared__ u16 Bs[128 * 32];
  f32x4 acc[4][4];
#pragma unroll
  for (int i = 0; i < 4; ++i)
#pragma unroll
    for (int j = 0; j < 4; ++j) acc[i][j] = (f32x4){0.f, 0.f, 0.f, 0.f};

  const int m0 = blockIdx.x * 128;
  const int n0g = blockIdx.y * 128;
  gemm_tile_128(A + (size_t)m0 * 1024, Bw + (size_t)n0g * 1024, 1024, As, Bs, acc);

  const int tid = threadIdx.x, lane = tid & 63, wave = tid >> 6;
  const int l16 = lane & 15, q4 = lane >> 4;
  const int wm = (wave >> 1) * 64, wn = (wave & 1) * 64;
  const int which = n0g >> 10;       // 0=Q,1=K,2=V (uniform per block)
  const int nb = n0g & 1023;
  u16* dst = (which == 0) ? q16 : ((which == 1) ? k16 : v16);

#pragma unroll
  for (int im = 0; im < 4; ++im)
#pragma unroll
    for (int in = 0; in < 4; ++in)
#pragma unroll
      for (int reg = 0; reg < 4; ++reg) {
        float v = acc[im][in][reg];
        int m = m0 + wm + im * 16 + q4 * 4 + reg;
        int nn = nb + wn + in * 16 + l16;
        int b = m >> 12, t = m & 4095;
        int h = nn >> 6, d = nn & 63;
        dst[((size_t)(b * HH + h) * TT + t) * 64 + d] = f2bf(v);
      }
}

// ---------------- plain out GEMM (fp32 epilogue) ----------------
__global__ __launch_bounds__(256) void k_gemm_out(const u16* __restrict__ A,
                                                  const u16* __restrict__ Bw,
                                                  float* __restrict__ C) {
  __shared__ u16 As[128 * 32];
  __shared__ u16 Bs[128 * 32];
  f32x4 acc[4][4];
#pragma unroll
  for (int i = 0; i < 4; ++i)
#pragma unroll
    for (int j = 0; j < 4; ++j) acc[i][j] = (f32x4){0.f, 0.f, 0.f, 0.f};

  const int m0 = blockIdx.x * 128;
  const int n0 = blockIdx.y * 128;
  gemm_tile_128(A + (size_t)m0 * 1024, Bw + (size_t)n0 * 1024, 1024, As, Bs, acc);

  const int tid = threadIdx.x, lane = tid & 63, wave = tid >> 6;
  const int l16 = lane & 15, q4 = lane >> 4;
  const int wm = (wave >> 1) * 64, wn = (wave & 1) * 64;
#pragma unroll
  for (int im = 0; im < 4; ++im)
#pragma unroll
    for (int in = 0; in < 4; ++in)
#pragma unroll
      for (int reg = 0; reg < 4; ++reg) {
        int m = m0 + wm + im * 16 + q4 * 4 + reg;
        int n = n0 + wn + in * 16 + l16;
        C[(size_t)m * 1024 + n] = acc[im][in][reg];
      }
}

// ---------------- stage 2: rope(K) -> write logits -> softmax -> slot_state ----------------
// grid: 1024 blocks = 64 (b*h) x 16 t-blocks; each block loops 2 chunks of 128 t
__global__ __launch_bounds__(256) void k_stage2(const u16* __restrict__ K16g,
                                                const u16* __restrict__ V16g,
                                                const float* __restrict__ SKg,
                                                const float* __restrict__ rc,
                                                const float* __restrict__ rs,
                                                float* __restrict__ SSb) {
  const int tid = threadIdx.x, lane = tid & 63, wave = tid >> 6;
  const int l16 = lane & 15, q4 = lane >> 4, q8 = q4 * 8;
  const int bh = blockIdx.x >> 4, cb = blockIdx.x & 15;
  const int h = bh & 15;

  __shared__ u16 Ks[128 * 88];    // [t][d] stride 88 (16B-aligned rows, ~2-way banks)
  __shared__ u16 Vs[64 * 136];    // [d][t] stride 136
  __shared__ u16 SKs[64 * 88];    // [s][d]
  u16* ww = Ks;                   // reuse as WW^T [s=64][t=128] stride 136 (fits in Ks)

  const float* skh = SKg + (size_t)h * (SSLOTS * DD);
  for (int i = tid; i < 4096; i += 256)
    SKs[(i >> 6) * 88 + (i & 63)] = f2bf(skh[i]);

  f32x4 a2[4];
#pragma unroll
  for (int in = 0; in < 4; ++in) a2[in] = (f32x4){0.f, 0.f, 0.f, 0.f};

  const int w32 = wave * 32;
  for (int cc = 0; cc < 2; ++cc) {
    const int tg0 = cb * 256 + cc * 128;
    __syncthreads();   // SKs visible (cc=0) / prev-iter LDS reads done (cc=1)

    const u16* ks = K16g + ((size_t)bh * TT + tg0) * 64;
    for (int idx = tid; idx < 1024; idx += 256) {
      int t = idx >> 3, p = idx & 7;
      us8v kv = *(const us8v*)(ks + (size_t)t * 64 + p * 8);
      int fi = (tg0 + t) * 32 + ((p * 8) & 31);
      us8v kr = rope8(kv, rc + fi, rs + fi);
      *(us8v*)&Ks[t * 88 + p * 8] = kr;
    }
    const u16* vsrc = V16g + ((size_t)bh * TT + tg0) * 64;
    for (int idx = tid; idx < 1024; idx += 256) {
      int t = idx & 127, dg = idx >> 7;
      us8v vv = *(const us8v*)(vsrc + (size_t)t * 64 + dg * 8);
#pragma unroll
      for (int j = 0; j < 8; ++j) Vs[(dg * 8 + j) * 136 + t] = vv[j];
    }
    __syncthreads();

    // MFMA1: WL[t][s] = K . SK^T   (wave owns 32 t-rows)
    f32x4 a1[2][4];
#pragma unroll
    for (int im = 0; im < 2; ++im)
#pragma unroll
      for (int in = 0; in < 4; ++in) a1[im][in] = (f32x4){0.f, 0.f, 0.f, 0.f};
#pragma unroll
    for (int ksx = 0; ksx < 2; ++ksx) {
      s16x8 afr0 = *(const s16x8*)&Ks[(w32 + l16) * 88 + ksx * 32 + q8];
      s16x8 afr1 = *(const s16x8*)&Ks[(w32 + 16 + l16) * 88 + ksx * 32 + q8];
#pragma unroll
      for (int in = 0; in < 4; ++in) {
        s16x8 bfr = *(const s16x8*)&SKs[(in * 16 + l16) * 88 + ksx * 32 + q8];
        a1[0][in] = MFMA16(afr0, bfr, a1[0][in]);
        a1[1][in] = MFMA16(afr1, bfr, a1[1][in]);
      }
    }
    __syncthreads();   // all waves done reading Ks before ww overwrite

    // softmax over s (64) per t-row; write WW^T bf16 into ww[s][t]
#pragma unroll
    for (int im = 0; im < 2; ++im)
#pragma unroll
      for (int reg = 0; reg < 4; ++reg) {
        float v0 = a1[im][0][reg] * 0.125f, v1 = a1[im][1][reg] * 0.125f;
        float v2 = a1[im][2][reg] * 0.125f, v3 = a1[im][3][reg] * 0.125f;
        float mx = fmaxf(fmaxf(v0, v1), fmaxf(v2, v3));
#pragma unroll
        for (int m = 1; m < 16; m <<= 1) mx = fmaxf(mx, __shfl_xor(mx, m));
        float e0 = __expf(v0 - mx), e1 = __expf(v1 - mx);
        float e2 = __expf(v2 - mx), e3 = __expf(v3 - mx);
        float sm = e0 + e1 + e2 + e3;
#pragma unroll
        for (int m = 1; m < 16; m <<= 1) sm += __shfl_xor(sm, m);
        float inv = 1.0f / sm;
        int tl = w32 + im * 16 + q4 * 4 + reg;
        ww[(l16) * 136 + tl]      = f2bf(e0 * inv);
        ww[(16 + l16) * 136 + tl] = f2bf(e1 * inv);
        ww[(32 + l16) * 136 + tl] = f2bf(e2 * inv);
        ww[(48 + l16) * 136 + tl] = f2bf(e3 * inv);
      }
    __syncthreads();

    // MFMA2: SS[s][d] += WW^T . V   (wave owns 16 s-rows, k = 128 t)
#pragma unroll
    for (int ksx = 0; ksx < 4; ++ksx) {
      s16x8 afr = *(const s16x8*)&ww[(wave * 16 + l16) * 136 + ksx * 32 + q8];
#pragma unroll
      for (int in = 0; in < 4; ++in) {
        s16x8 bfr = *(const s16x8*)&Vs[(in * 16 + l16) * 136 + ksx * 32 + q8];
        a2[in] = MFMA16(afr, bfr, a2[in]);
      }
    }
  }

  const float invT = 1.0f / (float)TT;
#pragma unroll
  for (int in = 0; in < 4; ++in)
#pragma unroll
    for (int reg = 0; reg < 4; ++reg) {
      int s = wave * 16 + q4 * 4 + reg;
      int d = in * 16 + l16;
      atomicAdd(&SSb[(size_t)bh * 4096 + s * 64 + d], a2[in][reg] * invT);
    }
}

// ---------------- stage 3: rope(Q) -> read logits -> softmax -> read_out ----------------
// grid: 1024 blocks = 64 (b*h) x 16 chunks of 256 t
__global__ __launch_bounds__(256) void k_stage3(const u16* __restrict__ Q16g,
                                                const float* __restrict__ SSg,
                                                const float* __restrict__ rc,
                                                const float* __restrict__ rs,
                                                u16* __restrict__ RO) {
  const int tid = threadIdx.x, lane = tid & 63, wave = tid >> 6;
  const int l16 = lane & 15, q4 = lane >> 4, q8 = q4 * 8;
  const int bh = blockIdx.x >> 4, ck = blockIdx.x & 15;
  const int b = bh >> 4, h = bh & 15;
  const int tg0 = ck * 256;

  __shared__ u16 Qs[256 * 88];      // [t][d]; reused as RW [t][s] (same rows)
  __shared__ u16 ss_sd[64 * 88];    // SS[s][d]
  __shared__ u16 ss_ds[64 * 88];    // SS^T[d][s]
  u16* RWs = Qs;

  const float* ssp = SSg + (size_t)bh * 4096;
  for (int i = tid; i < 4096; i += 256) {
    u16 u = f2bf(ssp[i]);
    int s = i >> 6, d = i & 63;
    ss_sd[s * 88 + d] = u;
    ss_ds[d * 88 + s] = u;
  }
  const u16* qsrc = Q16g + ((size_t)bh * TT + tg0) * 64;
  for (int idx = tid; idx < 2048; idx += 256) {
    int t = idx >> 3, p = idx & 7;
    us8v qv = *(const us8v*)(qsrc + (size_t)t * 64 + p * 8);
    int fi = (tg0 + t) * 32 + ((p * 8) & 31);
    us8v qr = rope8(qv, rc + fi, rs + fi);
    *(us8v*)&Qs[t * 88 + p * 8] = qr;
  }
  __syncthreads();

  const int w64 = wave * 64;
  // MFMA3: RL[t][s] = Q . SS^T
  f32x4 a3[4][4];
#pragma unroll
  for (int i = 0; i < 4; ++i)
#pragma unroll
    for (int j = 0; j < 4; ++j) a3[i][j] = (f32x4){0.f, 0.f, 0.f, 0.f};
#pragma unroll
  for (int ksx = 0; ksx < 2; ++ksx) {
    s16x8 afr[4];
#pragma unroll
    for (int im = 0; im < 4; ++im)
      afr[im] = *(const s16x8*)&Qs[(w64 + im * 16 + l16) * 88 + ksx * 32 + q8];
#pragma unroll
    for (int in = 0; in < 4; ++in) {
      s16x8 bfr = *(const s16x8*)&ss_sd[(in * 16 + l16) * 88 + ksx * 32 + q8];
#pragma unroll
      for (int im = 0; im < 4; ++im) a3[im][in] = MFMA16(afr[im], bfr, a3[im][in]);
    }
  }
  __syncthreads();

  // softmax over s, write RW[t][s] bf16
#pragma unroll
  for (int im = 0; im < 4; ++im)
#pragma unroll
    for (int reg = 0; reg < 4; ++reg) {
      float v0 = a3[im][0][reg] * 0.125f, v1 = a3[im][1][reg] * 0.125f;
      float v2 = a3[im][2][reg] * 0.125f, v3 = a3[im][3][reg] * 0.125f;
      float mx = fmaxf(fmaxf(v0, v1), fmaxf(v2, v3));
#pragma unroll
      for (int m = 1; m < 16; m <<= 1) mx = fmaxf(mx, __shfl_xor(mx, m));
      float e0 = __expf(v0 - mx), e1 = __expf(v1 - mx);
      float e2 = __expf(v2 - mx), e3 = __expf(v3 - mx);
      float sm = e0 + e1 + e2 + e3;
#pragma unroll
      for (int m = 1; m < 16; m <<= 1) sm += __shfl_xor(sm, m);
      float inv = 1.0f / sm;
      int tl = w64 + im * 16 + q4 * 4 + reg;
      RWs[tl * 88 + l16]      = f2bf(e0 * inv);
      RWs[tl * 88 + 16 + l16] = f2bf(e1 * inv);
      RWs[tl * 88 + 32 + l16] = f2bf(e2 * inv);
      RWs[tl * 88 + 48 + l16] = f2bf(e3 * inv);
    }
  __syncthreads();

  // MFMA4: RO[t][d] = RW . SS
  f32x4 a4[4][4];
#pragma unroll
  for (int i = 0; i < 4; ++i)
#pragma unroll
    for (int j = 0; j < 4; ++j) a4[i][j] = (f32x4){0.f, 0.f, 0.f, 0.f};
#pragma unroll
  for (int ksx = 0; ksx < 2; ++ksx) {
    s16x8 afr[4];
#pragma unroll
    for (int im = 0; im < 4; ++im)
      afr[im] = *(const s16x8*)&RWs[(w64 + im * 16 + l16) * 88 + ksx * 32 + q8];
#pragma unroll
    for (int in = 0; in < 4; ++in) {
      s16x8 bfr = *(const s16x8*)&ss_ds[(in * 16 + l16) * 88 + ksx * 32 + q8];
#pragma unroll
      for (int im = 0; im < 4; ++im) a4[im][in] = MFMA16(afr[im], bfr, a4[im][in]);
    }
  }

  // epilogue: RO bf16 [m][e] with m=b*T+t, e=h*64+d
#pragma unroll
  for (int im = 0; im < 4; ++im)
#pragma unroll
    for (int in = 0; in < 4; ++in)
#pragma unroll
      for (int reg = 0; reg < 4; ++reg) {
        int t = tg0 + w64 + im * 16 + q4 * 4 + reg;
        int d = in * 16 + l16;
        RO[((size_t)b * TT + t) * 1024 + h * 64 + d] = f2bf(a4[im][in][reg]);
      }
}

// ---------------- launch ----------------
extern "C" void kernel_launch(void* const* d_in, const int* in_sizes, int n_in,
                              void* d_out, int out_size, void* d_ws, size_t ws_size,
                              hipStream_t stream) {
  const float* x  = (const float*)d_in[0];
  const float* Wq = (const float*)d_in[1];
  const float* Wk = (const float*)d_in[2];
  const float* Wv = (const float*)d_in[3];
  const float* Wo = (const float*)d_in[4];
  const float* SK = (const float*)d_in[5];
  float* out = (float*)d_out;

  // workspace carve (needs ~145 MB)
  char* w = (char*)d_ws;
  u16* x16 = (u16*)w;   w += (size_t)MM * EE * 2;          // 33.5 MB
  u16* W16 = (u16*)w;   w += (size_t)3 * EE * EE * 2;      // 6.3 MB
  u16* Wo16 = (u16*)w;  w += (size_t)EE * EE * 2;          // 2.1 MB
  u16* Q16 = (u16*)w;   w += (size_t)BB * HH * TT * DD * 2; // 33.5 MB
  u16* K16 = (u16*)w;   w += (size_t)BB * HH * TT * DD * 2;
  u16* V16 = (u16*)w;   w += (size_t)BB * HH * TT * DD * 2;
  float* SSb = (float*)w; w += (size_t)BB * HH * SSLOTS * DD * 4; // 1 MB
  float* rc = (float*)w;  w += (size_t)TT * 32 * 4;
  float* rs = (float*)w;  w += (size_t)TT * 32 * 4;
  u16* RO16 = x16;  // x16 dead after QKV GEMM

  if ((size_t)(w - (char*)d_ws) > ws_size) return;  // ws too small -> loud failure

  k_cvt<<<16384, 256, 0, stream>>>(x, x16, MM * EE);
  k_cvt<<<1024, 256, 0, stream>>>(Wq, W16, EE * EE);
  k_cvt<<<1024, 256, 0, stream>>>(Wk, W16 + EE * EE, EE * EE);
  k_cvt<<<1024, 256, 0, stream>>>(Wv, W16 + 2 * EE * EE, EE * EE);
  k_cvt<<<1024, 256, 0, stream>>>(Wo, Wo16, EE * EE);
  k_rope<<<512, 256, 0, stream>>>(rc, rs);

  k_gemm_qkv<<<dim3(MM / 128, 3 * EE / 128), 256, 0, stream>>>(x16, W16, Q16, K16, V16);

  hipMemsetAsync(SSb, 0, (size_t)BB * HH * SSLOTS * DD * 4, stream);
  k_stage2<<<1024, 256, 0, stream>>>(K16, V16, SK, rc, rs, SSb);
  k_stage3<<<1024, 256, 0, stream>>>(Q16, SSb, rc, rs, RO16);

  k_gemm_out<<<dim3(MM / 128, EE / 128), 256, 0, stream>>>(RO16, Wo16, out);
}

// Round 3
// 369.097 us; speedup vs baseline: 1.2381x; 1.0346x over previous
//
#include <hip/hip_runtime.h>
#include <cstdint>
#include <cstddef>

// Problem constants
#define BB 4
#define TT 4096
#define EE 1024
#define HH 16
#define SSLOTS 64
#define DD 64
#define MM (BB*TT)   // 16384

typedef unsigned short u16;
typedef __attribute__((ext_vector_type(8))) short s16x8;     // 8 bf16 (4 VGPRs) MFMA frag
typedef __attribute__((ext_vector_type(4))) float f32x4;     // MFMA acc
typedef __attribute__((ext_vector_type(8))) unsigned short us8v;
typedef __attribute__((ext_vector_type(4))) unsigned short us4v;

#define MFMA16(a, b, c) __builtin_amdgcn_mfma_f32_16x16x32_bf16((a), (b), (c), 0, 0, 0)

__device__ __forceinline__ u16 f2bf(float x) {
  union { float f; uint32_t u; } c; c.f = x;
  uint32_t u = c.u;
  u += 0x7fffu + ((u >> 16) & 1u);   // round-to-nearest-even
  return (u16)(u >> 16);
}

__device__ __forceinline__ float bf2f(u16 x) {
  union { uint32_t u; float f; } c; c.u = ((uint32_t)x) << 16;
  return c.f;
}

// async global->LDS, 16B per lane. LDS dest must be base + lane*16 (wave-contiguous).
__device__ __forceinline__ void async16(const void* g, void* l) {
  auto lp = reinterpret_cast<__attribute__((address_space(3))) void*>(
      reinterpret_cast<uintptr_t>(l));
  auto gp = reinterpret_cast<const __attribute__((address_space(1))) void*>(
      reinterpret_cast<uintptr_t>(g));
  __builtin_amdgcn_global_load_lds(gp, lp, 16, 0, 0);
}

// Apply RoPE to an 8-wide bf16 chunk at feature offset d0=p*8 of row t.
__device__ __forceinline__ us8v rope8(us8v kv, const float* __restrict__ rcp,
                                      const float* __restrict__ rsp) {
  float e[8];
#pragma unroll
  for (int m = 0; m < 8; ++m) e[m] = bf2f((u16)kv[m]);
  us8v o;
#pragma unroll
  for (int j = 0; j < 4; ++j) {
    float c0 = rcp[2 * j], c1 = rcp[2 * j + 1];
    float s0 = rsp[2 * j], s1 = rsp[2 * j + 1];
    o[2 * j]     = f2bf(e[2 * j] * c0 - e[2 * j + 1] * s0);
    o[2 * j + 1] = f2bf(e[2 * j + 1] * c1 + e[2 * j] * s1);
  }
  return o;
}

// ---------------- conversion kernels ----------------
__global__ __launch_bounds__(256) void k_cvt(const float* __restrict__ s,
                                             u16* __restrict__ d, int n) {
  int i = (blockIdx.x * 256 + threadIdx.x) * 4;
  if (i >= n) return;
  float4 v = *(const float4*)(s + i);
  us4v o = { f2bf(v.x), f2bf(v.y), f2bf(v.z), f2bf(v.w) };
  *(us4v*)(d + i) = o;
}

// all 4 weight matrices in one launch (1024 blocks each)
__global__ __launch_bounds__(256) void k_cvt4(const float* __restrict__ w0,
                                              const float* __restrict__ w1,
                                              const float* __restrict__ w2,
                                              const float* __restrict__ w3,
                                              u16* __restrict__ dW,
                                              u16* __restrict__ dWo) {
  int sel = blockIdx.x >> 10;
  const float* s = (sel == 0) ? w0 : (sel == 1) ? w1 : (sel == 2) ? w2 : w3;
  u16* d = (sel < 3) ? (dW + (size_t)sel * EE * EE) : dWo;
  int i = ((blockIdx.x & 1023) * 256 + threadIdx.x) * 4;
  float4 v = *(const float4*)(s + i);
  us4v o = { f2bf(v.x), f2bf(v.y), f2bf(v.z), f2bf(v.w) };
  *(us4v*)(d + i) = o;
}

__global__ __launch_bounds__(256) void k_rope(float* __restrict__ rc, float* __restrict__ rs) {
  int i = blockIdx.x * 256 + threadIdx.x;
  if (i >= TT * 32) return;
  int t = i >> 5, f = i & 31;
  double invf = pow(10000.0, -(double)(2 * f) / 64.0);
  double th = fmod((double)t * invf, 6.28318530717958647692528676655900577);
  rc[i] = (float)cos(th);
  rs[i] = (float)sin(th);
}

// ---------------- shared GEMM mainloop: C(128x128) = A(128xK) * B(128xK)^T ----------------
__device__ __forceinline__ void gemm_tile_128(const u16* __restrict__ Ablk,
                                              const u16* __restrict__ Bblk,
                                              int K, u16* As, u16* Bs,
                                              f32x4 acc[4][4]) {
  const int tid = threadIdx.x;
  const int lane = tid & 63, wave = tid >> 6;
  const int l16 = lane & 15, q8 = (lane >> 4) * 8;
  const int wm = (wave >> 1) * 64, wn = (wave & 1) * 64;
  const int ar = tid >> 2, ac = (tid & 3) * 8;
  const u16* Ag0 = Ablk + (size_t)ar * K + ac;
  const u16* Ag1 = Ablk + (size_t)(ar + 64) * K + ac;
  const u16* Bg0 = Bblk + (size_t)ar * K + ac;
  const u16* Bg1 = Bblk + (size_t)(ar + 64) * K + ac;
  u16* Al0 = As + ar * 32 + ac;
  u16* Al1 = As + (ar + 64) * 32 + ac;
  u16* Bl0 = Bs + ar * 32 + ac;
  u16* Bl1 = Bs + (ar + 64) * 32 + ac;

  for (int k0 = 0; k0 < K; k0 += 32) {
    async16(Ag0 + k0, Al0);
    async16(Ag1 + k0, Al1);
    async16(Bg0 + k0, Bl0);
    async16(Bg1 + k0, Bl1);
    __syncthreads();
    s16x8 af[4], bf[4];
#pragma unroll
    for (int i = 0; i < 4; ++i) {
      af[i] = *(const s16x8*)(As + (wm + i * 16 + l16) * 32 + q8);
      bf[i] = *(const s16x8*)(Bs + (wn + i * 16 + l16) * 32 + q8);
    }
#pragma unroll
    for (int im = 0; im < 4; ++im)
#pragma unroll
      for (int in = 0; in < 4; ++in)
        acc[im][in] = MFMA16(af[im], bf[in], acc[im][in]);
    __syncthreads();
  }
}

// ---------------- fused QKV GEMM (rope applied later in stage2/3) ----------------
// grid: (24 n-tiles, 128 m-tiles) — n fastest so consecutive blocks share the A m-tile
__global__ __launch_bounds__(256) void k_gemm_qkv(const u16* __restrict__ A,
                                                  const u16* __restrict__ Bw,
                                                  u16* __restrict__ q16,
                                                  u16* __restrict__ k16,
                                                  u16* __restrict__ v16) {
  __shared__ u16 As[128 * 32];
  __shared__ u16 Bs[128 * 32];
  f32x4 acc[4][4];
#pragma unroll
  for (int i = 0; i < 4; ++i)
#pragma unroll
    for (int j = 0; j < 4; ++j) acc[i][j] = (f32x4){0.f, 0.f, 0.f, 0.f};

  const int m0 = blockIdx.y * 128;
  const int n0g = blockIdx.x * 128;
  gemm_tile_128(A + (size_t)m0 * 1024, Bw + (size_t)n0g * 1024, 1024, As, Bs, acc);

  const int tid = threadIdx.x, lane = tid & 63, wave = tid >> 6;
  const int l16 = lane & 15, q4 = lane >> 4;
  const int wm = (wave >> 1) * 64, wn = (wave & 1) * 64;
  const int which = n0g >> 10;       // 0=Q,1=K,2=V (uniform per block)
  const int nb = n0g & 1023;
  u16* dst = (which == 0) ? q16 : ((which == 1) ? k16 : v16);

#pragma unroll
  for (int im = 0; im < 4; ++im)
#pragma unroll
    for (int in = 0; in < 4; ++in)
#pragma unroll
      for (int reg = 0; reg < 4; ++reg) {
        float v = acc[im][in][reg];
        int m = m0 + wm + im * 16 + q4 * 4 + reg;
        int nn = nb + wn + in * 16 + l16;
        int b = m >> 12, t = m & 4095;
        int h = nn >> 6, d = nn & 63;
        dst[((size_t)(b * HH + h) * TT + t) * 64 + d] = f2bf(v);
      }
}

// ---------------- plain out GEMM (fp32 epilogue) ----------------
// grid: (8 n-tiles, 128 m-tiles) — n fastest for A-tile reuse
__global__ __launch_bounds__(256) void k_gemm_out(const u16* __restrict__ A,
                                                  const u16* __restrict__ Bw,
                                                  float* __restrict__ C) {
  __shared__ u16 As[128 * 32];
  __shared__ u16 Bs[128 * 32];
  f32x4 acc[4][4];
#pragma unroll
  for (int i = 0; i < 4; ++i)
#pragma unroll
    for (int j = 0; j < 4; ++j) acc[i][j] = (f32x4){0.f, 0.f, 0.f, 0.f};

  const int m0 = blockIdx.y * 128;
  const int n0 = blockIdx.x * 128;
  gemm_tile_128(A + (size_t)m0 * 1024, Bw + (size_t)n0 * 1024, 1024, As, Bs, acc);

  const int tid = threadIdx.x, lane = tid & 63, wave = tid >> 6;
  const int l16 = lane & 15, q4 = lane >> 4;
  const int wm = (wave >> 1) * 64, wn = (wave & 1) * 64;
#pragma unroll
  for (int im = 0; im < 4; ++im)
#pragma unroll
    for (int in = 0; in < 4; ++in)
#pragma unroll
      for (int reg = 0; reg < 4; ++reg) {
        int m = m0 + wm + im * 16 + q4 * 4 + reg;
        int n = n0 + wn + in * 16 + l16;
        C[(size_t)m * 1024 + n] = acc[im][in][reg];
      }
}

// ---------------- stage 2: rope(K) -> write logits -> softmax -> slot_state ----------------
// grid: 512 blocks = 64 (b*h) x 8 t-blocks; each block loops 4 chunks of 128 t
__global__ __launch_bounds__(256) void k_stage2(const u16* __restrict__ K16g,
                                                const u16* __restrict__ V16g,
                                                const float* __restrict__ SKg,
                                                const float* __restrict__ rc,
                                                const float* __restrict__ rs,
                                                float* __restrict__ SSb) {
  const int tid = threadIdx.x, lane = tid & 63, wave = tid >> 6;
  const int l16 = lane & 15, q4 = lane >> 4, q8 = q4 * 8;
  const int bh = blockIdx.x >> 3, cb = blockIdx.x & 7;
  const int h = bh & 15;

  __shared__ u16 Ks[128 * 88];    // [t][d] stride 88
  __shared__ u16 Vs[64 * 136];    // [d][t] stride 136
  __shared__ u16 SKs[64 * 88];    // [s][d]
  u16* ww = Ks;                   // reuse as WW^T [s=64][t=128] stride 136

  const float* skh = SKg + (size_t)h * (SSLOTS * DD);
  for (int i = tid; i < 4096; i += 256)
    SKs[(i >> 6) * 88 + (i & 63)] = f2bf(skh[i]);

  f32x4 a2[4];
#pragma unroll
  for (int in = 0; in < 4; ++in) a2[in] = (f32x4){0.f, 0.f, 0.f, 0.f};

  const int w32 = wave * 32;
  for (int cc = 0; cc < 4; ++cc) {
    const int tg0 = cb * 512 + cc * 128;
    __syncthreads();   // SKs visible (cc=0) / prev-iter LDS reads done

    const u16* ks = K16g + ((size_t)bh * TT + tg0) * 64;
    for (int idx = tid; idx < 1024; idx += 256) {
      int t = idx >> 3, p = idx & 7;
      us8v kv = *(const us8v*)(ks + (size_t)t * 64 + p * 8);
      int fi = (tg0 + t) * 32 + ((p * 8) & 31);
      us8v kr = rope8(kv, rc + fi, rs + fi);
      *(us8v*)&Ks[t * 88 + p * 8] = kr;
    }
    const u16* vsrc = V16g + ((size_t)bh * TT + tg0) * 64;
    for (int idx = tid; idx < 1024; idx += 256) {
      int t = idx & 127, dg = idx >> 7;
      us8v vv = *(const us8v*)(vsrc + (size_t)t * 64 + dg * 8);
#pragma unroll
      for (int j = 0; j < 8; ++j) Vs[(dg * 8 + j) * 136 + t] = vv[j];
    }
    __syncthreads();

    // MFMA1: WL[t][s] = K . SK^T   (wave owns 32 t-rows)
    f32x4 a1[2][4];
#pragma unroll
    for (int im = 0; im < 2; ++im)
#pragma unroll
      for (int in = 0; in < 4; ++in) a1[im][in] = (f32x4){0.f, 0.f, 0.f, 0.f};
#pragma unroll
    for (int ksx = 0; ksx < 2; ++ksx) {
      s16x8 afr0 = *(const s16x8*)&Ks[(w32 + l16) * 88 + ksx * 32 + q8];
      s16x8 afr1 = *(const s16x8*)&Ks[(w32 + 16 + l16) * 88 + ksx * 32 + q8];
#pragma unroll
      for (int in = 0; in < 4; ++in) {
        s16x8 bfr = *(const s16x8*)&SKs[(in * 16 + l16) * 88 + ksx * 32 + q8];
        a1[0][in] = MFMA16(afr0, bfr, a1[0][in]);
        a1[1][in] = MFMA16(afr1, bfr, a1[1][in]);
      }
    }
    __syncthreads();   // all waves done reading Ks before ww overwrite

    // softmax over s (64) per t-row; write WW^T bf16 into ww[s][t]
#pragma unroll
    for (int im = 0; im < 2; ++im)
#pragma unroll
      for (int reg = 0; reg < 4; ++reg) {
        float v0 = a1[im][0][reg] * 0.125f, v1 = a1[im][1][reg] * 0.125f;
        float v2 = a1[im][2][reg] * 0.125f, v3 = a1[im][3][reg] * 0.125f;
        float mx = fmaxf(fmaxf(v0, v1), fmaxf(v2, v3));
#pragma unroll
        for (int m = 1; m < 16; m <<= 1) mx = fmaxf(mx, __shfl_xor(mx, m));
        float e0 = __expf(v0 - mx), e1 = __expf(v1 - mx);
        float e2 = __expf(v2 - mx), e3 = __expf(v3 - mx);
        float sm = e0 + e1 + e2 + e3;
#pragma unroll
        for (int m = 1; m < 16; m <<= 1) sm += __shfl_xor(sm, m);
        float inv = 1.0f / sm;
        int tl = w32 + im * 16 + q4 * 4 + reg;
        ww[(l16) * 136 + tl]      = f2bf(e0 * inv);
        ww[(16 + l16) * 136 + tl] = f2bf(e1 * inv);
        ww[(32 + l16) * 136 + tl] = f2bf(e2 * inv);
        ww[(48 + l16) * 136 + tl] = f2bf(e3 * inv);
      }
    __syncthreads();

    // MFMA2: SS[s][d] += WW^T . V   (wave owns 16 s-rows, k = 128 t)
#pragma unroll
    for (int ksx = 0; ksx < 4; ++ksx) {
      s16x8 afr = *(const s16x8*)&ww[(wave * 16 + l16) * 136 + ksx * 32 + q8];
#pragma unroll
      for (int in = 0; in < 4; ++in) {
        s16x8 bfr = *(const s16x8*)&Vs[(in * 16 + l16) * 136 + ksx * 32 + q8];
        a2[in] = MFMA16(afr, bfr, a2[in]);
      }
    }
  }

  const float invT = 1.0f / (float)TT;
#pragma unroll
  for (int in = 0; in < 4; ++in)
#pragma unroll
    for (int reg = 0; reg < 4; ++reg) {
      int s = wave * 16 + q4 * 4 + reg;
      int d = in * 16 + l16;
      atomicAdd(&SSb[(size_t)bh * 4096 + s * 64 + d], a2[in][reg] * invT);
    }
}

// ---------------- stage 3: rope(Q) -> read logits -> softmax -> read_out ----------------
// grid: 2048 blocks = 64 (b*h) x 32 chunks of 128 t; 44 KB LDS -> 3 blocks/CU
__global__ __launch_bounds__(256) void k_stage3(const u16* __restrict__ Q16g,
                                                const float* __restrict__ SSg,
                                                const float* __restrict__ rc,
                                                const float* __restrict__ rs,
                                                u16* __restrict__ RO) {
  const int tid = threadIdx.x, lane = tid & 63, wave = tid >> 6;
  const int l16 = lane & 15, q4 = lane >> 4, q8 = q4 * 8;
  const int bh = blockIdx.x >> 5, ck = blockIdx.x & 31;
  const int b = bh >> 4, h = bh & 15;
  const int tg0 = ck * 128;

  __shared__ u16 Qs[128 * 88];      // [t][d]; reused as RW [t][s]
  __shared__ u16 ss_sd[64 * 88];    // SS[s][d]
  __shared__ u16 ss_ds[64 * 88];    // SS^T[d][s]
  u16* RWs = Qs;

  const float* ssp = SSg + (size_t)bh * 4096;
  for (int i = tid; i < 4096; i += 256) {
    u16 u = f2bf(ssp[i]);
    int s = i >> 6, d = i & 63;
    ss_sd[s * 88 + d] = u;
    ss_ds[d * 88 + s] = u;
  }
  const u16* qsrc = Q16g + ((size_t)bh * TT + tg0) * 64;
  for (int idx = tid; idx < 1024; idx += 256) {
    int t = idx >> 3, p = idx & 7;
    us8v qv = *(const us8v*)(qsrc + (size_t)t * 64 + p * 8);
    int fi = (tg0 + t) * 32 + ((p * 8) & 31);
    us8v qr = rope8(qv, rc + fi, rs + fi);
    *(us8v*)&Qs[t * 88 + p * 8] = qr;
  }
  __syncthreads();

  const int w32 = wave * 32;
  // MFMA3: RL[t][s] = Q . SS^T  (wave owns 32 t-rows)
  f32x4 a3[2][4];
#pragma unroll
  for (int i = 0; i < 2; ++i)
#pragma unroll
    for (int j = 0; j < 4; ++j) a3[i][j] = (f32x4){0.f, 0.f, 0.f, 0.f};
#pragma unroll
  for (int ksx = 0; ksx < 2; ++ksx) {
    s16x8 afr[2];
#pragma unroll
    for (int im = 0; im < 2; ++im)
      afr[im] = *(const s16x8*)&Qs[(w32 + im * 16 + l16) * 88 + ksx * 32 + q8];
#pragma unroll
    for (int in = 0; in < 4; ++in) {
      s16x8 bfr = *(const s16x8*)&ss_sd[(in * 16 + l16) * 88 + ksx * 32 + q8];
#pragma unroll
      for (int im = 0; im < 2; ++im) a3[im][in] = MFMA16(afr[im], bfr, a3[im][in]);
    }
  }
  __syncthreads();

  // softmax over s, write RW[t][s] bf16
#pragma unroll
  for (int im = 0; im < 2; ++im)
#pragma unroll
    for (int reg = 0; reg < 4; ++reg) {
      float v0 = a3[im][0][reg] * 0.125f, v1 = a3[im][1][reg] * 0.125f;
      float v2 = a3[im][2][reg] * 0.125f, v3 = a3[im][3][reg] * 0.125f;
      float mx = fmaxf(fmaxf(v0, v1), fmaxf(v2, v3));
#pragma unroll
      for (int m = 1; m < 16; m <<= 1) mx = fmaxf(mx, __shfl_xor(mx, m));
      float e0 = __expf(v0 - mx), e1 = __expf(v1 - mx);
      float e2 = __expf(v2 - mx), e3 = __expf(v3 - mx);
      float sm = e0 + e1 + e2 + e3;
#pragma unroll
      for (int m = 1; m < 16; m <<= 1) sm += __shfl_xor(sm, m);
      float inv = 1.0f / sm;
      int tl = w32 + im * 16 + q4 * 4 + reg;
      RWs[tl * 88 + l16]      = f2bf(e0 * inv);
      RWs[tl * 88 + 16 + l16] = f2bf(e1 * inv);
      RWs[tl * 88 + 32 + l16] = f2bf(e2 * inv);
      RWs[tl * 88 + 48 + l16] = f2bf(e3 * inv);
    }
  __syncthreads();

  // MFMA4: RO[t][d] = RW . SS
  f32x4 a4[2][4];
#pragma unroll
  for (int i = 0; i < 2; ++i)
#pragma unroll
    for (int j = 0; j < 4; ++j) a4[i][j] = (f32x4){0.f, 0.f, 0.f, 0.f};
#pragma unroll
  for (int ksx = 0; ksx < 2; ++ksx) {
    s16x8 afr[2];
#pragma unroll
    for (int im = 0; im < 2; ++im)
      afr[im] = *(const s16x8*)&RWs[(w32 + im * 16 + l16) * 88 + ksx * 32 + q8];
#pragma unroll
    for (int in = 0; in < 4; ++in) {
      s16x8 bfr = *(const s16x8*)&ss_ds[(in * 16 + l16) * 88 + ksx * 32 + q8];
#pragma unroll
      for (int im = 0; im < 2; ++im) a4[im][in] = MFMA16(afr[im], bfr, a4[im][in]);
    }
  }

  // epilogue: RO bf16 [m][e] with m=b*T+t, e=h*64+d
#pragma unroll
  for (int im = 0; im < 2; ++im)
#pragma unroll
    for (int in = 0; in < 4; ++in)
#pragma unroll
      for (int reg = 0; reg < 4; ++reg) {
        int t = tg0 + w32 + im * 16 + q4 * 4 + reg;
        int d = in * 16 + l16;
        RO[((size_t)b * TT + t) * 1024 + h * 64 + d] = f2bf(a4[im][in][reg]);
      }
}

// ---------------- launch ----------------
extern "C" void kernel_launch(void* const* d_in, const int* in_sizes, int n_in,
                              void* d_out, int out_size, void* d_ws, size_t ws_size,
                              hipStream_t stream) {
  const float* x  = (const float*)d_in[0];
  const float* Wq = (const float*)d_in[1];
  const float* Wk = (const float*)d_in[2];
  const float* Wv = (const float*)d_in[3];
  const float* Wo = (const float*)d_in[4];
  const float* SK = (const float*)d_in[5];
  float* out = (float*)d_out;

  // workspace carve (needs ~145 MB)
  char* w = (char*)d_ws;
  u16* x16 = (u16*)w;   w += (size_t)MM * EE * 2;          // 33.5 MB
  u16* W16 = (u16*)w;   w += (size_t)3 * EE * EE * 2;      // 6.3 MB
  u16* Wo16 = (u16*)w;  w += (size_t)EE * EE * 2;          // 2.1 MB
  u16* Q16 = (u16*)w;   w += (size_t)BB * HH * TT * DD * 2; // 33.5 MB
  u16* K16 = (u16*)w;   w += (size_t)BB * HH * TT * DD * 2;
  u16* V16 = (u16*)w;   w += (size_t)BB * HH * TT * DD * 2;
  float* SSb = (float*)w; w += (size_t)BB * HH * SSLOTS * DD * 4; // 1 MB
  float* rc = (float*)w;  w += (size_t)TT * 32 * 4;
  float* rs = (float*)w;  w += (size_t)TT * 32 * 4;
  u16* RO16 = x16;  // x16 dead after QKV GEMM

  if ((size_t)(w - (char*)d_ws) > ws_size) return;  // ws too small -> loud failure

  k_cvt<<<16384, 256, 0, stream>>>(x, x16, MM * EE);
  k_cvt4<<<4096, 256, 0, stream>>>(Wq, Wk, Wv, Wo, W16, Wo16);
  k_rope<<<512, 256, 0, stream>>>(rc, rs);

  k_gemm_qkv<<<dim3(3 * EE / 128, MM / 128), 256, 0, stream>>>(x16, W16, Q16, K16, V16);

  hipMemsetAsync(SSb, 0, (size_t)BB * HH * SSLOTS * DD * 4, stream);
  k_stage2<<<512, 256, 0, stream>>>(K16, V16, SK, rc, rs, SSb);
  k_stage3<<<2048, 256, 0, stream>>>(Q16, SSb, rc, rs, RO16);

  k_gemm_out<<<dim3(EE / 128, MM / 128), 256, 0, stream>>>(RO16, Wo16, out);
}

// Round 4
// 349.287 us; speedup vs baseline: 1.3083x; 1.0567x over previous
//
#include <hip/hip_runtime.h>
#include <cstdint>
#include <cstddef>

// Problem constants
#define BB 4
#define TT 4096
#define EE 1024
#define HH 16
#define SSLOTS 64
#define DD 64
#define MM (BB*TT)   // 16384

typedef unsigned short u16;
typedef __attribute__((ext_vector_type(8))) short s16x8;     // 8 bf16 (4 VGPRs) MFMA frag
typedef __attribute__((ext_vector_type(4))) float f32x4;     // MFMA acc
typedef __attribute__((ext_vector_type(8))) unsigned short us8v;
typedef __attribute__((ext_vector_type(4))) unsigned short us4v;

#define MFMA16(a, b, c) __builtin_amdgcn_mfma_f32_16x16x32_bf16((a), (b), (c), 0, 0, 0)

__device__ __forceinline__ u16 f2bf(float x) {
  union { float f; uint32_t u; } c; c.f = x;
  uint32_t u = c.u;
  u += 0x7fffu + ((u >> 16) & 1u);   // round-to-nearest-even
  return (u16)(u >> 16);
}

__device__ __forceinline__ float bf2f(u16 x) {
  union { uint32_t u; float f; } c; c.u = ((uint32_t)x) << 16;
  return c.f;
}

// async global->LDS, 16B per lane. LDS dest must be base + lane*16 (wave-contiguous).
__device__ __forceinline__ void async16(const void* g, void* l) {
  auto lp = reinterpret_cast<__attribute__((address_space(3))) void*>(
      reinterpret_cast<uintptr_t>(l));
  auto gp = reinterpret_cast<const __attribute__((address_space(1))) void*>(
      reinterpret_cast<uintptr_t>(g));
  __builtin_amdgcn_global_load_lds(gp, lp, 16, 0, 0);
}

// Apply RoPE to an 8-wide bf16 chunk at feature offset d0=p*8 of row t.
__device__ __forceinline__ us8v rope8(us8v kv, const float* __restrict__ rcp,
                                      const float* __restrict__ rsp) {
  float e[8];
#pragma unroll
  for (int m = 0; m < 8; ++m) e[m] = bf2f((u16)kv[m]);
  us8v o;
#pragma unroll
  for (int j = 0; j < 4; ++j) {
    float c0 = rcp[2 * j], c1 = rcp[2 * j + 1];
    float s0 = rsp[2 * j], s1 = rsp[2 * j + 1];
    o[2 * j]     = f2bf(e[2 * j] * c0 - e[2 * j + 1] * s0);
    o[2 * j + 1] = f2bf(e[2 * j + 1] * c1 + e[2 * j] * s1);
  }
  return o;
}

// ---------------- fused prep: cvt x, cvt 4 weights, rope tables — one launch ----------------
__global__ __launch_bounds__(256) void k_prep(const float* __restrict__ x,
                                              const float* __restrict__ w0,
                                              const float* __restrict__ w1,
                                              const float* __restrict__ w2,
                                              const float* __restrict__ w3,
                                              u16* __restrict__ x16,
                                              u16* __restrict__ dW,
                                              u16* __restrict__ dWo,
                                              float* __restrict__ rc,
                                              float* __restrict__ rs) {
  int bid = blockIdx.x;
  if (bid < 16384) {                    // x: 16.7M floats
    int i = (bid * 256 + threadIdx.x) * 4;
    float4 v = *(const float4*)(x + i);
    us4v o = { f2bf(v.x), f2bf(v.y), f2bf(v.z), f2bf(v.w) };
    *(us4v*)(x16 + i) = o;
  } else if (bid < 16384 + 4096) {      // 4 weight matrices, 1024 blocks each
    int bb = bid - 16384;
    int sel = bb >> 10;
    const float* s = (sel == 0) ? w0 : (sel == 1) ? w1 : (sel == 2) ? w2 : w3;
    u16* d = (sel < 3) ? (dW + (size_t)sel * EE * EE) : dWo;
    int i = ((bb & 1023) * 256 + threadIdx.x) * 4;
    float4 v = *(const float4*)(s + i);
    us4v o = { f2bf(v.x), f2bf(v.y), f2bf(v.z), f2bf(v.w) };
    *(us4v*)(d + i) = o;
  } else {                              // rope: 131072 entries, 512 blocks
    int i = (bid - 16384 - 4096) * 256 + threadIdx.x;
    int t = i >> 5, f = i & 31;
    double invf = pow(10000.0, -(double)(2 * f) / 64.0);
    double th = fmod((double)t * invf, 6.28318530717958647692528676655900577);
    rc[i] = (float)cos(th);
    rs[i] = (float)sin(th);
  }
}

// ---------------- shared GEMM mainloop: C(128x128) = A(128xK) * B(128xK)^T ----------------
// BK=64 as two sequential 32-wide panels: halves barrier count vs m97 BK=32 while
// keeping the conflict-free 32-wide LDS layout and async16 lane-contiguity.
// LDS: As/Bs each 2 panels x 128x32 u16 = 16 KB (32 KB total).
__device__ __forceinline__ void gemm_tile_128(const u16* __restrict__ Ablk,
                                              const u16* __restrict__ Bblk,
                                              int K, u16* As, u16* Bs,
                                              f32x4 acc[4][4]) {
  const int tid = threadIdx.x;
  const int lane = tid & 63, wave = tid >> 6;
  const int l16 = lane & 15, q8 = (lane >> 4) * 8;
  const int wm = (wave >> 1) * 64, wn = (wave & 1) * 64;
  const int ar = tid >> 2, ac = (tid & 3) * 8;
  const u16* Ag0 = Ablk + (size_t)ar * K + ac;
  const u16* Ag1 = Ablk + (size_t)(ar + 64) * K + ac;
  const u16* Bg0 = Bblk + (size_t)ar * K + ac;
  const u16* Bg1 = Bblk + (size_t)(ar + 64) * K + ac;
  u16* Al0 = As + ar * 32 + ac;
  u16* Al1 = As + (ar + 64) * 32 + ac;
  u16* Bl0 = Bs + ar * 32 + ac;
  u16* Bl1 = Bs + (ar + 64) * 32 + ac;

  for (int k0 = 0; k0 < K; k0 += 64) {
    // panel 0: cols k0..k0+31 ; panel 1: cols k0+32..k0+63 (LDS offset +4096 u16)
    async16(Ag0 + k0, Al0);
    async16(Ag1 + k0, Al1);
    async16(Ag0 + k0 + 32, Al0 + 4096);
    async16(Ag1 + k0 + 32, Al1 + 4096);
    async16(Bg0 + k0, Bl0);
    async16(Bg1 + k0, Bl1);
    async16(Bg0 + k0 + 32, Bl0 + 4096);
    async16(Bg1 + k0 + 32, Bl1 + 4096);
    __syncthreads();
#pragma unroll
    for (int p = 0; p < 2; ++p) {
      const u16* Ap = As + p * 4096;
      const u16* Bp = Bs + p * 4096;
      s16x8 af[4], bf[4];
#pragma unroll
      for (int i = 0; i < 4; ++i) {
        af[i] = *(const s16x8*)(Ap + (wm + i * 16 + l16) * 32 + q8);
        bf[i] = *(const s16x8*)(Bp + (wn + i * 16 + l16) * 32 + q8);
      }
#pragma unroll
      for (int im = 0; im < 4; ++im)
#pragma unroll
        for (int in = 0; in < 4; ++in)
          acc[im][in] = MFMA16(af[im], bf[in], acc[im][in]);
    }
    __syncthreads();
  }
}

// ---------------- fused QKV GEMM (rope applied later in stage2/3) ----------------
// grid: (128 m-tiles, 24 n-tiles) m-fastest — proven layout (R2: 97 MB fetch)
__global__ __launch_bounds__(256) void k_gemm_qkv(const u16* __restrict__ A,
                                                  const u16* __restrict__ Bw,
                                                  u16* __restrict__ q16,
                                                  u16* __restrict__ k16,
                                                  u16* __restrict__ v16) {
  __shared__ u16 As[2 * 128 * 32];
  __shared__ u16 Bs[2 * 128 * 32];
  f32x4 acc[4][4];
#pragma unroll
  for (int i = 0; i < 4; ++i)
#pragma unroll
    for (int j = 0; j < 4; ++j) acc[i][j] = (f32x4){0.f, 0.f, 0.f, 0.f};

  const int m0 = blockIdx.x * 128;
  const int n0g = blockIdx.y * 128;
  gemm_tile_128(A + (size_t)m0 * 1024, Bw + (size_t)n0g * 1024, 1024, As, Bs, acc);

  const int tid = threadIdx.x, lane = tid & 63, wave = tid >> 6;
  const int l16 = lane & 15, q4 = lane >> 4;
  const int wm = (wave >> 1) * 64, wn = (wave & 1) * 64;
  const int which = n0g >> 10;       // 0=Q,1=K,2=V (uniform per block)
  const int nb = n0g & 1023;
  u16* dst = (which == 0) ? q16 : ((which == 1) ? k16 : v16);

#pragma unroll
  for (int im = 0; im < 4; ++im)
#pragma unroll
    for (int in = 0; in < 4; ++in)
#pragma unroll
      for (int reg = 0; reg < 4; ++reg) {
        float v = acc[im][in][reg];
        int m = m0 + wm + im * 16 + q4 * 4 + reg;
        int nn = nb + wn + in * 16 + l16;
        int b = m >> 12, t = m & 4095;
        int h = nn >> 6, d = nn & 63;
        dst[((size_t)(b * HH + h) * TT + t) * 64 + d] = f2bf(v);
      }
}

// ---------------- plain out GEMM (fp32 epilogue) ----------------
// grid: (128 m-tiles, 8 n-tiles) m-fastest
__global__ __launch_bounds__(256) void k_gemm_out(const u16* __restrict__ A,
                                                  const u16* __restrict__ Bw,
                                                  float* __restrict__ C) {
  __shared__ u16 As[2 * 128 * 32];
  __shared__ u16 Bs[2 * 128 * 32];
  f32x4 acc[4][4];
#pragma unroll
  for (int i = 0; i < 4; ++i)
#pragma unroll
    for (int j = 0; j < 4; ++j) acc[i][j] = (f32x4){0.f, 0.f, 0.f, 0.f};

  const int m0 = blockIdx.x * 128;
  const int n0 = blockIdx.y * 128;
  gemm_tile_128(A + (size_t)m0 * 1024, Bw + (size_t)n0 * 1024, 1024, As, Bs, acc);

  const int tid = threadIdx.x, lane = tid & 63, wave = tid >> 6;
  const int l16 = lane & 15, q4 = lane >> 4;
  const int wm = (wave >> 1) * 64, wn = (wave & 1) * 64;
#pragma unroll
  for (int im = 0; im < 4; ++im)
#pragma unroll
    for (int in = 0; in < 4; ++in)
#pragma unroll
      for (int reg = 0; reg < 4; ++reg) {
        int m = m0 + wm + im * 16 + q4 * 4 + reg;
        int n = n0 + wn + in * 16 + l16;
        C[(size_t)m * 1024 + n] = acc[im][in][reg];
      }
}

// ---------------- stage 2: rope(K) -> write logits -> softmax -> slot_state ----------------
// grid: 512 blocks = 64 (b*h) x 8 t-blocks; each block loops 4 chunks of 128 t
__global__ __launch_bounds__(256) void k_stage2(const u16* __restrict__ K16g,
                                                const u16* __restrict__ V16g,
                                                const float* __restrict__ SKg,
                                                const float* __restrict__ rc,
                                                const float* __restrict__ rs,
                                                float* __restrict__ SSb) {
  const int tid = threadIdx.x, lane = tid & 63, wave = tid >> 6;
  const int l16 = lane & 15, q4 = lane >> 4, q8 = q4 * 8;
  const int bh = blockIdx.x >> 3, cb = blockIdx.x & 7;
  const int h = bh & 15;

  __shared__ u16 Ks[128 * 88];    // [t][d] stride 88
  __shared__ u16 Vs[64 * 136];    // [d][t] stride 136
  __shared__ u16 SKs[64 * 88];    // [s][d]
  u16* ww = Ks;                   // reuse as WW^T [s=64][t=128] stride 136

  const float* skh = SKg + (size_t)h * (SSLOTS * DD);
  for (int i = tid; i < 4096; i += 256)
    SKs[(i >> 6) * 88 + (i & 63)] = f2bf(skh[i]);

  f32x4 a2[4];
#pragma unroll
  for (int in = 0; in < 4; ++in) a2[in] = (f32x4){0.f, 0.f, 0.f, 0.f};

  const int w32 = wave * 32;
  for (int cc = 0; cc < 4; ++cc) {
    const int tg0 = cb * 512 + cc * 128;
    __syncthreads();   // SKs visible (cc=0) / prev-iter LDS reads done

    const u16* ks = K16g + ((size_t)bh * TT + tg0) * 64;
    for (int idx = tid; idx < 1024; idx += 256) {
      int t = idx >> 3, p = idx & 7;
      us8v kv = *(const us8v*)(ks + (size_t)t * 64 + p * 8);
      int fi = (tg0 + t) * 32 + ((p * 8) & 31);
      us8v kr = rope8(kv, rc + fi, rs + fi);
      *(us8v*)&Ks[t * 88 + p * 8] = kr;
    }
    const u16* vsrc = V16g + ((size_t)bh * TT + tg0) * 64;
    for (int idx = tid; idx < 1024; idx += 256) {
      int t = idx & 127, dg = idx >> 7;
      us8v vv = *(const us8v*)(vsrc + (size_t)t * 64 + dg * 8);
#pragma unroll
      for (int j = 0; j < 8; ++j) Vs[(dg * 8 + j) * 136 + t] = vv[j];
    }
    __syncthreads();

    // MFMA1: WL[t][s] = K . SK^T   (wave owns 32 t-rows)
    f32x4 a1[2][4];
#pragma unroll
    for (int im = 0; im < 2; ++im)
#pragma unroll
      for (int in = 0; in < 4; ++in) a1[im][in] = (f32x4){0.f, 0.f, 0.f, 0.f};
#pragma unroll
    for (int ksx = 0; ksx < 2; ++ksx) {
      s16x8 afr0 = *(const s16x8*)&Ks[(w32 + l16) * 88 + ksx * 32 + q8];
      s16x8 afr1 = *(const s16x8*)&Ks[(w32 + 16 + l16) * 88 + ksx * 32 + q8];
#pragma unroll
      for (int in = 0; in < 4; ++in) {
        s16x8 bfr = *(const s16x8*)&SKs[(in * 16 + l16) * 88 + ksx * 32 + q8];
        a1[0][in] = MFMA16(afr0, bfr, a1[0][in]);
        a1[1][in] = MFMA16(afr1, bfr, a1[1][in]);
      }
    }
    __syncthreads();   // all waves done reading Ks before ww overwrite

    // softmax over s (64) per t-row; write WW^T bf16 into ww[s][t]
#pragma unroll
    for (int im = 0; im < 2; ++im)
#pragma unroll
      for (int reg = 0; reg < 4; ++reg) {
        float v0 = a1[im][0][reg] * 0.125f, v1 = a1[im][1][reg] * 0.125f;
        float v2 = a1[im][2][reg] * 0.125f, v3 = a1[im][3][reg] * 0.125f;
        float mx = fmaxf(fmaxf(v0, v1), fmaxf(v2, v3));
#pragma unroll
        for (int m = 1; m < 16; m <<= 1) mx = fmaxf(mx, __shfl_xor(mx, m));
        float e0 = __expf(v0 - mx), e1 = __expf(v1 - mx);
        float e2 = __expf(v2 - mx), e3 = __expf(v3 - mx);
        float sm = e0 + e1 + e2 + e3;
#pragma unroll
        for (int m = 1; m < 16; m <<= 1) sm += __shfl_xor(sm, m);
        float inv = 1.0f / sm;
        int tl = w32 + im * 16 + q4 * 4 + reg;
        ww[(l16) * 136 + tl]      = f2bf(e0 * inv);
        ww[(16 + l16) * 136 + tl] = f2bf(e1 * inv);
        ww[(32 + l16) * 136 + tl] = f2bf(e2 * inv);
        ww[(48 + l16) * 136 + tl] = f2bf(e3 * inv);
      }
    __syncthreads();

    // MFMA2: SS[s][d] += WW^T . V   (wave owns 16 s-rows, k = 128 t)
#pragma unroll
    for (int ksx = 0; ksx < 4; ++ksx) {
      s16x8 afr = *(const s16x8*)&ww[(wave * 16 + l16) * 136 + ksx * 32 + q8];
#pragma unroll
      for (int in = 0; in < 4; ++in) {
        s16x8 bfr = *(const s16x8*)&Vs[(in * 16 + l16) * 136 + ksx * 32 + q8];
        a2[in] = MFMA16(afr, bfr, a2[in]);
      }
    }
  }

  const float invT = 1.0f / (float)TT;
#pragma unroll
  for (int in = 0; in < 4; ++in)
#pragma unroll
    for (int reg = 0; reg < 4; ++reg) {
      int s = wave * 16 + q4 * 4 + reg;
      int d = in * 16 + l16;
      atomicAdd(&SSb[(size_t)bh * 4096 + s * 64 + d], a2[in][reg] * invT);
    }
}

// ---------------- stage 3: rope(Q) -> read logits -> softmax -> read_out ----------------
// grid: 2048 blocks = 64 (b*h) x 32 chunks of 128 t; 44 KB LDS
__global__ __launch_bounds__(256) void k_stage3(const u16* __restrict__ Q16g,
                                                const float* __restrict__ SSg,
                                                const float* __restrict__ rc,
                                                const float* __restrict__ rs,
                                                u16* __restrict__ RO) {
  const int tid = threadIdx.x, lane = tid & 63, wave = tid >> 6;
  const int l16 = lane & 15, q4 = lane >> 4, q8 = q4 * 8;
  const int bh = blockIdx.x >> 5, ck = blockIdx.x & 31;
  const int b = bh >> 4, h = bh & 15;
  const int tg0 = ck * 128;

  __shared__ u16 Qs[128 * 88];      // [t][d]; reused as RW [t][s]
  __shared__ u16 ss_sd[64 * 88];    // SS[s][d]
  __shared__ u16 ss_ds[64 * 88];    // SS^T[d][s]
  u16* RWs = Qs;

  const float* ssp = SSg + (size_t)bh * 4096;
  for (int i = tid; i < 4096; i += 256) {
    u16 u = f2bf(ssp[i]);
    int s = i >> 6, d = i & 63;
    ss_sd[s * 88 + d] = u;
    ss_ds[d * 88 + s] = u;
  }
  const u16* qsrc = Q16g + ((size_t)bh * TT + tg0) * 64;
  for (int idx = tid; idx < 1024; idx += 256) {
    int t = idx >> 3, p = idx & 7;
    us8v qv = *(const us8v*)(qsrc + (size_t)t * 64 + p * 8);
    int fi = (tg0 + t) * 32 + ((p * 8) & 31);
    us8v qr = rope8(qv, rc + fi, rs + fi);
    *(us8v*)&Qs[t * 88 + p * 8] = qr;
  }
  __syncthreads();

  const int w32 = wave * 32;
  // MFMA3: RL[t][s] = Q . SS^T  (wave owns 32 t-rows)
  f32x4 a3[2][4];
#pragma unroll
  for (int i = 0; i < 2; ++i)
#pragma unroll
    for (int j = 0; j < 4; ++j) a3[i][j] = (f32x4){0.f, 0.f, 0.f, 0.f};
#pragma unroll
  for (int ksx = 0; ksx < 2; ++ksx) {
    s16x8 afr[2];
#pragma unroll
    for (int im = 0; im < 2; ++im)
      afr[im] = *(const s16x8*)&Qs[(w32 + im * 16 + l16) * 88 + ksx * 32 + q8];
#pragma unroll
    for (int in = 0; in < 4; ++in) {
      s16x8 bfr = *(const s16x8*)&ss_sd[(in * 16 + l16) * 88 + ksx * 32 + q8];
#pragma unroll
      for (int im = 0; im < 2; ++im) a3[im][in] = MFMA16(afr[im], bfr, a3[im][in]);
    }
  }
  __syncthreads();

  // softmax over s, write RW[t][s] bf16
#pragma unroll
  for (int im = 0; im < 2; ++im)
#pragma unroll
    for (int reg = 0; reg < 4; ++reg) {
      float v0 = a3[im][0][reg] * 0.125f, v1 = a3[im][1][reg] * 0.125f;
      float v2 = a3[im][2][reg] * 0.125f, v3 = a3[im][3][reg] * 0.125f;
      float mx = fmaxf(fmaxf(v0, v1), fmaxf(v2, v3));
#pragma unroll
      for (int m = 1; m < 16; m <<= 1) mx = fmaxf(mx, __shfl_xor(mx, m));
      float e0 = __expf(v0 - mx), e1 = __expf(v1 - mx);
      float e2 = __expf(v2 - mx), e3 = __expf(v3 - mx);
      float sm = e0 + e1 + e2 + e3;
#pragma unroll
      for (int m = 1; m < 16; m <<= 1) sm += __shfl_xor(sm, m);
      float inv = 1.0f / sm;
      int tl = w32 + im * 16 + q4 * 4 + reg;
      RWs[tl * 88 + l16]      = f2bf(e0 * inv);
      RWs[tl * 88 + 16 + l16] = f2bf(e1 * inv);
      RWs[tl * 88 + 32 + l16] = f2bf(e2 * inv);
      RWs[tl * 88 + 48 + l16] = f2bf(e3 * inv);
    }
  __syncthreads();

  // MFMA4: RO[t][d] = RW . SS
  f32x4 a4[2][4];
#pragma unroll
  for (int i = 0; i < 2; ++i)
#pragma unroll
    for (int j = 0; j < 4; ++j) a4[i][j] = (f32x4){0.f, 0.f, 0.f, 0.f};
#pragma unroll
  for (int ksx = 0; ksx < 2; ++ksx) {
    s16x8 afr[2];
#pragma unroll
    for (int im = 0; im < 2; ++im)
      afr[im] = *(const s16x8*)&RWs[(w32 + im * 16 + l16) * 88 + ksx * 32 + q8];
#pragma unroll
    for (int in = 0; in < 4; ++in) {
      s16x8 bfr = *(const s16x8*)&ss_ds[(in * 16 + l16) * 88 + ksx * 32 + q8];
#pragma unroll
      for (int im = 0; im < 2; ++im) a4[im][in] = MFMA16(afr[im], bfr, a4[im][in]);
    }
  }

  // epilogue: RO bf16 [m][e] with m=b*T+t, e=h*64+d
#pragma unroll
  for (int im = 0; im < 2; ++im)
#pragma unroll
    for (int in = 0; in < 4; ++in)
#pragma unroll
      for (int reg = 0; reg < 4; ++reg) {
        int t = tg0 + w32 + im * 16 + q4 * 4 + reg;
        int d = in * 16 + l16;
        RO[((size_t)b * TT + t) * 1024 + h * 64 + d] = f2bf(a4[im][in][reg]);
      }
}

// ---------------- launch ----------------
extern "C" void kernel_launch(void* const* d_in, const int* in_sizes, int n_in,
                              void* d_out, int out_size, void* d_ws, size_t ws_size,
                              hipStream_t stream) {
  const float* x  = (const float*)d_in[0];
  const float* Wq = (const float*)d_in[1];
  const float* Wk = (const float*)d_in[2];
  const float* Wv = (const float*)d_in[3];
  const float* Wo = (const float*)d_in[4];
  const float* SK = (const float*)d_in[5];
  float* out = (float*)d_out;

  // workspace carve (needs ~145 MB)
  char* w = (char*)d_ws;
  u16* x16 = (u16*)w;   w += (size_t)MM * EE * 2;          // 33.5 MB
  u16* W16 = (u16*)w;   w += (size_t)3 * EE * EE * 2;      // 6.3 MB
  u16* Wo16 = (u16*)w;  w += (size_t)EE * EE * 2;          // 2.1 MB
  u16* Q16 = (u16*)w;   w += (size_t)BB * HH * TT * DD * 2; // 33.5 MB
  u16* K16 = (u16*)w;   w += (size_t)BB * HH * TT * DD * 2;
  u16* V16 = (u16*)w;   w += (size_t)BB * HH * TT * DD * 2;
  float* SSb = (float*)w; w += (size_t)BB * HH * SSLOTS * DD * 4; // 1 MB
  float* rc = (float*)w;  w += (size_t)TT * 32 * 4;
  float* rs = (float*)w;  w += (size_t)TT * 32 * 4;
  u16* RO16 = x16;  // x16 dead after QKV GEMM

  if ((size_t)(w - (char*)d_ws) > ws_size) return;  // ws too small -> loud failure

  k_prep<<<16384 + 4096 + 512, 256, 0, stream>>>(x, Wq, Wk, Wv, Wo, x16, W16, Wo16, rc, rs);

  k_gemm_qkv<<<dim3(MM / 128, 3 * EE / 128), 256, 0, stream>>>(x16, W16, Q16, K16, V16);

  hipMemsetAsync(SSb, 0, (size_t)BB * HH * SSLOTS * DD * 4, stream);
  k_stage2<<<512, 256, 0, stream>>>(K16, V16, SK, rc, rs, SSb);
  k_stage3<<<2048, 256, 0, stream>>>(Q16, SSb, rc, rs, RO16);

  k_gemm_out<<<dim3(MM / 128, EE / 128), 256, 0, stream>>>(RO16, Wo16, out);
}